// Round 6
// baseline (180.144 us; speedup 1.0000x reference)
//
#include <hip/hip_runtime.h>
#include <hip/hip_bf16.h>
#include <hip/hip_cooperative_groups.h>

namespace cg = cooperative_groups;

// HypergraphDecoder: B=2, N=1024, E=256, H=64, D=64, Hm=128
// Outputs (concat, f32): samples[2,1024,1024], mask_scores[2,1024,1024],
//                        entropy[2,1024,1024], w[1024]
// R6: coop kernel, 512 blocks x 256 thr (needs only 2 blocks/CU co-resident;
//     LDS 24.8KB allows 6). Phase 1: bx<256 proj_exp -> ws, bx 256..511 edge
//     MLP (4 rows/block, wave-per-row). grid.sync. Phase 2: 2 pair tiles per
//     block (tiles bx and bx+512 of the 1024-tile decomposition).
//     FALLBACK: if hipLaunchCooperativeKernel returns error (R5 failed this
//     way, unchecked), launch the proven R4 two-kernel path instead.
// History: R1 112.3 / R2 112.6 / R3 114.6 (shape-invariant -> ~95us harness
// poison/restore overhead), R4 108.9 (3->2 launches), R5 FAIL (coop@1024
// blocks rejected, nothing ran). Pair floor ~7us (134M v_rcp, trans-bound).

#define L2E 1.4426950408889634f
#define C2  2.8853900817779268f   // 2*log2(e)
#define LN2 0.6931471805599453f
#define RCP(x) __builtin_amdgcn_rcpf(x)
#define EXP2(x) __builtin_amdgcn_exp2f(x)
#define LOG2(x) __builtin_amdgcn_logf(x)

// ---------------- threefry2x32, key = (0,1) (jax.random.key(1)) -------------
__device__ __forceinline__ void threefry2x32_01(unsigned x0, unsigned x1,
                                                unsigned& o0, unsigned& o1) {
  const unsigned k0 = 0u, k1 = 1u;
  const unsigned k2 = 0x1BD11BDAu ^ k0 ^ k1;  // 0x1BD11BDB
#define TF_R(r) { x0 += x1; x1 = (x1 << r) | (x1 >> (32 - r)); x1 ^= x0; }
  x0 += k0; x1 += k1;
  TF_R(13) TF_R(15) TF_R(26) TF_R(6)
  x0 += k1; x1 += k2 + 1u;
  TF_R(17) TF_R(29) TF_R(16) TF_R(24)
  x0 += k2; x1 += k0 + 2u;
  TF_R(13) TF_R(15) TF_R(26) TF_R(6)
  x0 += k0; x1 += k1 + 3u;
  TF_R(17) TF_R(29) TF_R(16) TF_R(24)
  x0 += k1; x1 += k2 + 4u;
  TF_R(13) TF_R(15) TF_R(26) TF_R(6)
  x0 += k2; x1 += k0 + 5u;
#undef TF_R
  o0 = x0; o1 = x1;
}

__device__ __forceinline__ float tf_uniform(unsigned y) {
  // jax uniform f32: bitcast((bits>>9)|0x3f800000) - 1.0
  return __uint_as_float((y >> 9) | 0x3f800000u) - 1.0f;
}

// ---------------- shared device helpers -------------------------------------
// proj tile: 32r x 32c; r = b*1024+n; c<64 -> wl else wr; writes
// ws[mat*131072 + b*65536 + c*1024 + n] = exp2(C2*dot). lds needs 2144 floats.
__device__ __forceinline__ void proj_tile(
    float* lds, int t, int tileid, const float* __restrict__ enc,
    const float* __restrict__ wl, const float* __restrict__ wr,
    float* __restrict__ ws) {
  float* As = lds;          // [32][33]
  float* Ws = lds + 1056;   // [32][34]
  const int r0 = (tileid & 63) * 32;
  const int c0 = (tileid >> 6) * 32;
  const float* __restrict__ wmat = (c0 < 64) ? wl : wr;
  const int cbase = c0 & 63;
  const int ty = t >> 4, tx = t & 15;
  float acc[2][2] = {};
  for (int ec = 0; ec < 8; ++ec) {
    {
      const int rr = t >> 3, e4 = (t & 7) * 4;
      const float4 v = *(const float4*)(enc + (r0 + rr) * 256 + ec * 32 + e4);
      As[rr * 33 + e4] = v.x; As[rr * 33 + e4 + 1] = v.y;
      As[rr * 33 + e4 + 2] = v.z; As[rr * 33 + e4 + 3] = v.w;
      const float4 w = *(const float4*)(wmat + (ec * 32 + rr) * 64 + cbase + e4);
      Ws[rr * 34 + e4] = w.x; Ws[rr * 34 + e4 + 1] = w.y;
      Ws[rr * 34 + e4 + 2] = w.z; Ws[rr * 34 + e4 + 3] = w.w;
    }
    __syncthreads();
#pragma unroll
    for (int e = 0; e < 32; ++e) {
      const float a0 = As[(2 * ty) * 33 + e];
      const float a1 = As[(2 * ty + 1) * 33 + e];
      const float2 wv = *(const float2*)&Ws[e * 34 + 2 * tx];
      acc[0][0] = fmaf(a0, wv.x, acc[0][0]);
      acc[0][1] = fmaf(a0, wv.y, acc[0][1]);
      acc[1][0] = fmaf(a1, wv.x, acc[1][0]);
      acc[1][1] = fmaf(a1, wv.y, acc[1][1]);
    }
    __syncthreads();
  }
  const int matoff = (c0 < 64) ? 0 : 131072;
#pragma unroll
  for (int i = 0; i < 2; ++i) {
    const int r = r0 + 2 * ty + i;
    const int b = r >> 10, n = r & 1023;
#pragma unroll
    for (int j = 0; j < 2; ++j) {
      const int c = cbase + 2 * tx + j;
      ws[matoff + b * 65536 + c * 1024 + n] = EXP2(C2 * acc[i][j]);
    }
  }
}

// pair tile T in [0,1024): b=T>>9, i0=(T&31)*32, j0=((T>>5)&15)*64.
// lds needs 6208 floats. Caller must __syncthreads-protect LDS reuse.
__device__ __forceinline__ void pair_tile(
    float* lds, int t, int T, const float* __restrict__ ws,
    const float* __restrict__ u, const float* __restrict__ lb,
    float* __restrict__ out) {
  float* sA = lds;           // [64][32]
  float* sB = lds + 2048;    // [64][64]
  float* sU = lds + 6144;    // [64]
  const int b = T >> 9;
  const int i0 = (T & 31) * 32;
  const int j0 = ((T >> 5) & 15) * 64;
  const float* __restrict__ srcA = ws + b * 65536;
  const float* __restrict__ srcB = ws + 131072 + b * 65536;

  {
    const int h = t >> 3, c = (t & 7) * 4;
    *(float4*)(sA + h * 32 + c) = *(const float4*)(srcA + h * 1024 + i0 + c);
    *(float4*)(sA + (h + 32) * 32 + c) =
        *(const float4*)(srcA + (h + 32) * 1024 + i0 + c);
  }
  {
    const int h = t >> 4, c = (t & 15) * 4;
#pragma unroll
    for (int q = 0; q < 4; ++q)
      *(float4*)(sB + (h + 16 * q) * 64 + c) =
          *(const float4*)(srcB + (h + 16 * q) * 1024 + j0 + c);
  }
  if (t < 64) sU[t] = u[t];
  __syncthreads();

  const int ia = (t >> 4) * 2;   // 2 consecutive i (broadcast b64 read)
  const int ja = (t & 15) * 4;   // 4 consecutive j (2-way-free b128 read)
  float acc[2][4] = {};          // acc = sum_h u_h * rcp(A*B + 1)
#pragma unroll
  for (int h4 = 0; h4 < 16; ++h4) {
    const float4 uc = *(const float4*)(sU + h4 * 4);
#pragma unroll
    for (int hh = 0; hh < 4; ++hh) {
      const int h = h4 * 4 + hh;
      const float uh = (&uc.x)[hh];
      const float2 av = *(const float2*)(sA + h * 32 + ia);
      const float4 bv = *(const float4*)(sB + h * 64 + ja);
      const float a[2] = {av.x, av.y};
      const float bb[4] = {bv.x, bv.y, bv.z, bv.w};
#pragma unroll
      for (int ii = 0; ii < 2; ++ii)
#pragma unroll
        for (int jj = 0; jj < 4; ++jj)
          acc[ii][jj] = fmaf(uh, RCP(fmaf(a[ii], bb[jj], 1.0f)), acc[ii][jj]);
    }
  }

  float uv = sU[t & 63];
#pragma unroll
  for (int off = 32; off > 0; off >>= 1) uv += __shfl_xor(uv, off);
  const float su = uv + lb[0];

  float* __restrict__ outS = out + b * 1048576;
  float* __restrict__ outM = out + 2097152 + b * 1048576;
  float* __restrict__ outE = out + 4194304 + b * 1048576;
#pragma unroll
  for (int ii = 0; ii < 2; ++ii) {
    const int gi = i0 + ia + ii;
    const unsigned mb = (unsigned)(gi * 1024 + j0 + ja);
    float4 sv, ev, smv;
#pragma unroll
    for (int jj = 0; jj < 4; ++jj) {
      const int gj = j0 + ja + jj;
      unsigned y0, y1;
      threefry2x32_01(mb + (unsigned)jj, mb + (unsigned)jj + 1048576u, y0, y1);
      const float uu = tf_uniform(b ? y1 : y0);
      float s = fmaf(-2.0f, acc[ii][jj], su);
      if (gi == gj) s -= 1e8f;               // diagonal mask
      const float ex = EXP2(-s * L2E);
      const float p = RCP(1.0f + ex);        // sigmoid (inf -> 0 on diag)
      const float em = EXP2(-fabsf(s) * L2E);
      const float ent = fmaxf(s, 0.0f) + LOG2(1.0f + em) * LN2 - s * p;
      (&sv.x)[jj] = s;
      (&ev.x)[jj] = ent;
      (&smv.x)[jj] = (uu < p) ? 1.0f : 0.0f;
    }
    const int base = gi * 1024 + j0 + ja;
    *(float4*)(outS + base) = smv;
    *(float4*)(outM + base) = sv;
    *(float4*)(outE + base) = ev;
  }
}

// edge MLP, 4 rows/block, one 64-lane wave per row, 2 h's per lane.
__device__ __forceinline__ void mlp_rows(
    float* lds, int t, int e0, const float* __restrict__ eq,
    const float* __restrict__ w1, const float* __restrict__ b1,
    const float* __restrict__ w2, const float* __restrict__ b2,
    float* __restrict__ wout) {
  float* eql = lds;  // [4][64]
  const int row = t >> 6, lane = t & 63;
  const int e = e0 + row;
  eql[row * 64 + lane] = eq[e * 64 + lane];
  __syncthreads();
  float acc0 = b1[lane], acc1 = b1[lane + 64];
#pragma unroll 8
  for (int k = 0; k < 64; ++k) {
    const float ev = eql[row * 64 + k];
    acc0 = fmaf(ev, w1[k * 128 + lane], acc0);
    acc1 = fmaf(ev, w1[k * 128 + 64 + lane], acc1);
  }
  float v = fmaxf(acc0, 0.0f) * w2[lane] + fmaxf(acc1, 0.0f) * w2[lane + 64];
#pragma unroll
  for (int off = 32; off > 0; off >>= 1) v += __shfl_xor(v, off);
  if (lane == 0) {
    const float l = v + b2[0];
    const float sp = fmaxf(l, 0.0f) + log1pf(expf(-fabsf(l)));
    wout[e] = sp + 1e-8f;
  }
}

// ---------------- coop kernel: 512 blocks x 256 threads ---------------------
__global__ __launch_bounds__(256, 2) void fused_kernel(
    const float* __restrict__ enc, const float* __restrict__ wl,
    const float* __restrict__ wr, float* __restrict__ ws,
    const float* __restrict__ eq, const float* __restrict__ w1,
    const float* __restrict__ b1, const float* __restrict__ w2,
    const float* __restrict__ b2, const float* __restrict__ u,
    const float* __restrict__ lb, float* __restrict__ out) {
  __shared__ float lds[6208];  // 24.8KB, aliased across phases
  const int t = threadIdx.x;
  const int bx = blockIdx.x;

  if (bx < 256) {
    proj_tile(lds, t, bx, enc, wl, wr, ws);
  } else {
    mlp_rows(lds, t, (bx - 256) * 4, eq, w1, b1, w2, b2, out + 6291456);
  }

  cg::this_grid().sync();

#pragma unroll
  for (int k = 0; k < 2; ++k) {
    __syncthreads();           // protect LDS reuse (phase1 / previous tile)
    pair_tile(lds, t, bx + 512 * k, ws, u, lb, out);
  }
}

// ---------------- fallback: proven R4 two-kernel path -----------------------
__global__ __launch_bounds__(256) void prep_kernel(
    const float* __restrict__ enc, const float* __restrict__ wl,
    const float* __restrict__ wr, float* __restrict__ ws,
    const float* __restrict__ eq, const float* __restrict__ w1,
    const float* __restrict__ b1, const float* __restrict__ w2,
    const float* __restrict__ b2, float* __restrict__ wout) {
  __shared__ float lds[2144];
  const int t = threadIdx.x;
  const int bx = blockIdx.x;
  if (bx < 256) {
    proj_tile(lds, t, bx, enc, wl, wr, ws);
  } else {
    mlp_rows(lds, t, (bx - 256) * 4, eq, w1, b1, w2, b2, wout);
  }
}

__global__ __launch_bounds__(256) void pair_kernel(
    const float* __restrict__ ws, const float* __restrict__ u,
    const float* __restrict__ lb, float* __restrict__ out) {
  __shared__ float lds[6208];
  const int T = blockIdx.x + (blockIdx.y << 5) + (blockIdx.z << 9);
  pair_tile(lds, threadIdx.x, T, ws, u, lb, out);
}

extern "C" void kernel_launch(void* const* d_in, const int* in_sizes, int n_in,
                              void* d_out, int out_size, void* d_ws, size_t ws_size,
                              hipStream_t stream) {
  const float* enc = (const float*)d_in[0];   // [2,1024,256]
  const float* wl  = (const float*)d_in[1];   // [256,64]
  const float* wr  = (const float*)d_in[2];   // [256,64]
  const float* u   = (const float*)d_in[3];   // [64]
  const float* lb  = (const float*)d_in[4];   // [1]
  const float* eq  = (const float*)d_in[5];   // [1024,64]
  const float* w1  = (const float*)d_in[6];   // [64,128]
  const float* b1  = (const float*)d_in[7];   // [128]
  const float* w2  = (const float*)d_in[8];   // [128,1]
  const float* b2  = (const float*)d_in[9];   // [1]
  float* out = (float*)d_out;
  float* wsf = (float*)d_ws;                  // 262144 floats = 1MB used

  void* args[] = {(void*)&enc, (void*)&wl, (void*)&wr, (void*)&wsf,
                  (void*)&eq,  (void*)&w1, (void*)&b1, (void*)&w2,
                  (void*)&b2,  (void*)&u,  (void*)&lb, (void*)&out};
  hipError_t rc = hipLaunchCooperativeKernel((const void*)fused_kernel,
                                             dim3(512), dim3(256), args, 0,
                                             stream);
  if (rc != hipSuccess) {
    // R4 path: two plain launches (proj+MLP fused, then pair tiles).
    prep_kernel<<<320, 256, 0, stream>>>(enc, wl, wr, wsf, eq, w1, b1, w2, b2,
                                         out + 6291456);
    pair_kernel<<<dim3(32, 16, 2), 256, 0, stream>>>(wsf, u, lb, out);
  }
}

// Round 7
// 109.521 us; speedup vs baseline: 1.6448x; 1.6448x over previous
//
#include <hip/hip_runtime.h>
#include <hip/hip_bf16.h>

// HypergraphDecoder: B=2, N=1024, E=256, H=64, D=64, Hm=128
// Outputs (concat, f32): samples[2,1024,1024], mask_scores[2,1024,1024],
//                        entropy[2,1024,1024], w[1024]
// R7: back to R4 two-launch structure (R6 coop added ~90us replay overhead).
//   pair v5: 32i x 64j tile, 1024 blocks (4/CU, 16 waves/CU), LDS 24.8KB.
//     - h batched by 4 with REGISTER PREFETCH of batch k+1 before computing
//       batch k (hides ~120cy LDS latency under ~220cy of VALU work)
//     - wave-staggered batch order (wave w starts at batch 4w, mod 16) so
//       same-block waves' LDS bubbles interleave instead of aligning
//   R6 evidence: pair phase idles ~80% (VALUBusy 20%), scales with
//   waves/SIMD x chains/thread -> latency-bound, not LDS-BW/VALU bound.
// History: R1 112.3 / R2 112.6 / R3 114.6 / R4 108.9 / R5 FAIL / R6 180.1.

#define L2E 1.4426950408889634f
#define C2  2.8853900817779268f   // 2*log2(e)
#define LN2 0.6931471805599453f
#define RCP(x) __builtin_amdgcn_rcpf(x)
#define EXP2(x) __builtin_amdgcn_exp2f(x)
#define LOG2(x) __builtin_amdgcn_logf(x)

// ---------------- threefry2x32, key = (0,1) (jax.random.key(1)) -------------
__device__ __forceinline__ void threefry2x32_01(unsigned x0, unsigned x1,
                                                unsigned& o0, unsigned& o1) {
  const unsigned k0 = 0u, k1 = 1u;
  const unsigned k2 = 0x1BD11BDAu ^ k0 ^ k1;  // 0x1BD11BDB
#define TF_R(r) { x0 += x1; x1 = (x1 << r) | (x1 >> (32 - r)); x1 ^= x0; }
  x0 += k0; x1 += k1;
  TF_R(13) TF_R(15) TF_R(26) TF_R(6)
  x0 += k1; x1 += k2 + 1u;
  TF_R(17) TF_R(29) TF_R(16) TF_R(24)
  x0 += k2; x1 += k0 + 2u;
  TF_R(13) TF_R(15) TF_R(26) TF_R(6)
  x0 += k0; x1 += k1 + 3u;
  TF_R(17) TF_R(29) TF_R(16) TF_R(24)
  x0 += k1; x1 += k2 + 4u;
  TF_R(13) TF_R(15) TF_R(26) TF_R(6)
  x0 += k2; x1 += k0 + 5u;
#undef TF_R
  o0 = x0; o1 = x1;
}

__device__ __forceinline__ float tf_uniform(unsigned y) {
  // jax uniform f32: bitcast((bits>>9)|0x3f800000) - 1.0
  return __uint_as_float((y >> 9) | 0x3f800000u) - 1.0f;
}

// ---------------- proj tile (32r x 32c) -------------------------------------
__device__ __forceinline__ void proj_tile(
    float* lds, int t, int tileid, const float* __restrict__ enc,
    const float* __restrict__ wl, const float* __restrict__ wr,
    float* __restrict__ ws) {
  float* As = lds;          // [32][33]
  float* Ws = lds + 1056;   // [32][34]
  const int r0 = (tileid & 63) * 32;
  const int c0 = (tileid >> 6) * 32;
  const float* __restrict__ wmat = (c0 < 64) ? wl : wr;
  const int cbase = c0 & 63;
  const int ty = t >> 4, tx = t & 15;
  float acc[2][2] = {};
  for (int ec = 0; ec < 8; ++ec) {
    {
      const int rr = t >> 3, e4 = (t & 7) * 4;
      const float4 v = *(const float4*)(enc + (r0 + rr) * 256 + ec * 32 + e4);
      As[rr * 33 + e4] = v.x; As[rr * 33 + e4 + 1] = v.y;
      As[rr * 33 + e4 + 2] = v.z; As[rr * 33 + e4 + 3] = v.w;
      const float4 w = *(const float4*)(wmat + (ec * 32 + rr) * 64 + cbase + e4);
      Ws[rr * 34 + e4] = w.x; Ws[rr * 34 + e4 + 1] = w.y;
      Ws[rr * 34 + e4 + 2] = w.z; Ws[rr * 34 + e4 + 3] = w.w;
    }
    __syncthreads();
#pragma unroll
    for (int e = 0; e < 32; ++e) {
      const float a0 = As[(2 * ty) * 33 + e];
      const float a1 = As[(2 * ty + 1) * 33 + e];
      const float2 wv = *(const float2*)&Ws[e * 34 + 2 * tx];
      acc[0][0] = fmaf(a0, wv.x, acc[0][0]);
      acc[0][1] = fmaf(a0, wv.y, acc[0][1]);
      acc[1][0] = fmaf(a1, wv.x, acc[1][0]);
      acc[1][1] = fmaf(a1, wv.y, acc[1][1]);
    }
    __syncthreads();
  }
  const int matoff = (c0 < 64) ? 0 : 131072;
#pragma unroll
  for (int i = 0; i < 2; ++i) {
    const int r = r0 + 2 * ty + i;
    const int b = r >> 10, n = r & 1023;
#pragma unroll
    for (int j = 0; j < 2; ++j) {
      const int c = cbase + 2 * tx + j;
      ws[matoff + b * 65536 + c * 1024 + n] = EXP2(C2 * acc[i][j]);
    }
  }
}

// ---------------- edge MLP (4 rows/block, wave per row) ---------------------
__device__ __forceinline__ void mlp_rows(
    float* lds, int t, int e0, const float* __restrict__ eq,
    const float* __restrict__ w1, const float* __restrict__ b1,
    const float* __restrict__ w2, const float* __restrict__ b2,
    float* __restrict__ wout) {
  float* eql = lds;  // [4][64]
  const int row = t >> 6, lane = t & 63;
  const int e = e0 + row;
  eql[row * 64 + lane] = eq[e * 64 + lane];
  __syncthreads();
  float acc0 = b1[lane], acc1 = b1[lane + 64];
#pragma unroll 8
  for (int k = 0; k < 64; ++k) {
    const float ev = eql[row * 64 + k];
    acc0 = fmaf(ev, w1[k * 128 + lane], acc0);
    acc1 = fmaf(ev, w1[k * 128 + 64 + lane], acc1);
  }
  float v = fmaxf(acc0, 0.0f) * w2[lane] + fmaxf(acc1, 0.0f) * w2[lane + 64];
#pragma unroll
  for (int off = 32; off > 0; off >>= 1) v += __shfl_xor(v, off);
  if (lane == 0) {
    const float l = v + b2[0];
    const float sp = fmaxf(l, 0.0f) + log1pf(expf(-fabsf(l)));
    wout[e] = sp + 1e-8f;
  }
}

__global__ __launch_bounds__(256) void prep_kernel(
    const float* __restrict__ enc, const float* __restrict__ wl,
    const float* __restrict__ wr, float* __restrict__ ws,
    const float* __restrict__ eq, const float* __restrict__ w1,
    const float* __restrict__ b1, const float* __restrict__ w2,
    const float* __restrict__ b2, float* __restrict__ wout) {
  __shared__ float lds[2144];
  const int t = threadIdx.x;
  const int bx = blockIdx.x;
  if (bx < 256) {
    proj_tile(lds, t, bx, enc, wl, wr, ws);
  } else {
    mlp_rows(lds, t, (bx - 256) * 4, eq, w1, b1, w2, b2, wout);
  }
}

// ---------------- pair kernel v5: pipelined + wave-staggered ----------------
// Tile 32i x 64j, grid (32,16,2) = 1024 blocks (4/CU). LDS 24.8KB.
__global__ __launch_bounds__(256, 4) void pair_kernel(
    const float* __restrict__ ws, const float* __restrict__ u,
    const float* __restrict__ lb, float* __restrict__ out) {
  __shared__ float sA[64 * 32];  // [h][i_local]
  __shared__ float sB[64 * 64];  // [h][j_local]
  __shared__ float sU[64];
  const int t = threadIdx.x;
  const int b = blockIdx.z;
  const int i0 = blockIdx.x * 32;
  const int j0 = blockIdx.y * 64;
  const float* __restrict__ srcA = ws + b * 65536;
  const float* __restrict__ srcB = ws + 131072 + b * 65536;

  {
    const int h = t >> 3, c = (t & 7) * 4;
    *(float4*)(sA + h * 32 + c) = *(const float4*)(srcA + h * 1024 + i0 + c);
    *(float4*)(sA + (h + 32) * 32 + c) =
        *(const float4*)(srcA + (h + 32) * 1024 + i0 + c);
  }
  {
    const int h = t >> 4, c = (t & 15) * 4;
#pragma unroll
    for (int q = 0; q < 4; ++q)
      *(float4*)(sB + (h + 16 * q) * 64 + c) =
          *(const float4*)(srcB + (h + 16 * q) * 1024 + j0 + c);
  }
  if (t < 64) sU[t] = u[t];
  __syncthreads();

  const int ia = (t >> 4) * 2;      // 2 consecutive i (broadcast b64 read)
  const int ja = (t & 15) * 4;      // 4 consecutive j (2-way-free b128 read)
  const int woff = (t >> 6) * 4;    // wave-staggered starting batch (0,4,8,12)

  float acc[2][4] = {};             // acc = sum_h u_h * rcp(A*B + 1)

  // batch = 4 h's. cur/nxt register sets; prefetch nxt before computing cur.
  float2 ac[4]; float4 bc[4]; float4 uc;
  {
    const int k = woff;             // first batch for this wave
    uc = *(const float4*)(sU + k * 4);
#pragma unroll
    for (int hh = 0; hh < 4; ++hh) {
      const int h = k * 4 + hh;
      ac[hh] = *(const float2*)(sA + h * 32 + ia);
      bc[hh] = *(const float4*)(sB + h * 64 + ja);
    }
  }

#pragma unroll 2
  for (int hb = 0; hb < 16; ++hb) {
    const int kn = ((hb + 1) & 15) == 0 ? woff
                                        : ((woff + hb + 1) & 15);
    // ---- prefetch next batch into nxt regs (issued before cur compute) ----
    float2 an[4]; float4 bn[4]; float4 un;
    un = *(const float4*)(sU + kn * 4);
#pragma unroll
    for (int hh = 0; hh < 4; ++hh) {
      const int h = kn * 4 + hh;
      an[hh] = *(const float2*)(sA + h * 32 + ia);
      bn[hh] = *(const float4*)(sB + h * 64 + ja);
    }
    // ---- compute current batch ----
#pragma unroll
    for (int hh = 0; hh < 4; ++hh) {
      const float uh = (&uc.x)[hh];
      const float a0 = ac[hh].x, a1 = ac[hh].y;
      const float bb[4] = {bc[hh].x, bc[hh].y, bc[hh].z, bc[hh].w};
#pragma unroll
      for (int jj = 0; jj < 4; ++jj) {
        acc[0][jj] = fmaf(uh, RCP(fmaf(a0, bb[jj], 1.0f)), acc[0][jj]);
        acc[1][jj] = fmaf(uh, RCP(fmaf(a1, bb[jj], 1.0f)), acc[1][jj]);
      }
    }
    // ---- rotate ----
    uc = un;
#pragma unroll
    for (int hh = 0; hh < 4; ++hh) { ac[hh] = an[hh]; bc[hh] = bn[hh]; }
  }

  // s = sum(u) + l_bias - 2*acc ; butterfly-reduce sum(u)
  float uv = sU[t & 63];
#pragma unroll
  for (int off = 32; off > 0; off >>= 1) uv += __shfl_xor(uv, off);
  const float su = uv + lb[0];

  float* __restrict__ outS = out + b * 1048576;
  float* __restrict__ outM = out + 2097152 + b * 1048576;
  float* __restrict__ outE = out + 4194304 + b * 1048576;
#pragma unroll
  for (int ii = 0; ii < 2; ++ii) {
    const int gi = i0 + ia + ii;
    const unsigned mb = (unsigned)(gi * 1024 + j0 + ja);
    float4 sv, ev, smv;
#pragma unroll
    for (int jj = 0; jj < 4; ++jj) {
      const int gj = j0 + ja + jj;
      // jax counter pair (m, m+2^20): out0 -> b=0 sample, out1 -> b=1 sample
      unsigned y0, y1;
      threefry2x32_01(mb + (unsigned)jj, mb + (unsigned)jj + 1048576u, y0, y1);
      const float uu = tf_uniform(b ? y1 : y0);
      float s = fmaf(-2.0f, acc[ii][jj], su);
      if (gi == gj) s -= 1e8f;               // diagonal mask
      const float ex = EXP2(-s * L2E);
      const float p = RCP(1.0f + ex);        // sigmoid (inf -> 0 on diag)
      const float em = EXP2(-fabsf(s) * L2E);
      const float ent = fmaxf(s, 0.0f) + LOG2(1.0f + em) * LN2 - s * p;
      (&sv.x)[jj] = s;
      (&ev.x)[jj] = ent;
      (&smv.x)[jj] = (uu < p) ? 1.0f : 0.0f;
    }
    const int base = gi * 1024 + j0 + ja;
    *(float4*)(outS + base) = smv;
    *(float4*)(outM + base) = sv;
    *(float4*)(outE + base) = ev;
  }
}

extern "C" void kernel_launch(void* const* d_in, const int* in_sizes, int n_in,
                              void* d_out, int out_size, void* d_ws, size_t ws_size,
                              hipStream_t stream) {
  const float* enc = (const float*)d_in[0];   // [2,1024,256]
  const float* wl  = (const float*)d_in[1];   // [256,64]
  const float* wr  = (const float*)d_in[2];   // [256,64]
  const float* u   = (const float*)d_in[3];   // [64]
  const float* lb  = (const float*)d_in[4];   // [1]
  const float* eq  = (const float*)d_in[5];   // [1024,64]
  const float* w1  = (const float*)d_in[6];   // [64,128]
  const float* b1  = (const float*)d_in[7];   // [128]
  const float* w2  = (const float*)d_in[8];   // [128,1]
  const float* b2  = (const float*)d_in[9];   // [1]
  float* out = (float*)d_out;
  float* wsf = (float*)d_ws;                  // 262144 floats = 1MB used

  prep_kernel<<<320, 256, 0, stream>>>(enc, wl, wr, wsf, eq, w1, b1, w2, b2,
                                       out + 6291456);
  pair_kernel<<<dim3(32, 16, 2), 256, 0, stream>>>(wsf, u, lb, out);
}

// Round 8
// 107.331 us; speedup vs baseline: 1.6784x; 1.0204x over previous
//
#include <hip/hip_runtime.h>
#include <hip/hip_bf16.h>

// HypergraphDecoder: B=2, N=1024, E=256, H=64, D=64, Hm=128
// Outputs (concat, f32): samples[2,1024,1024], mask_scores[2,1024,1024],
//                        entropy[2,1024,1024], w[1024]
// R8 (final): R4 structure (best measured, 108.9us). Pair = v3 loop (no
// stagger/prefetch -- R7 showed -0.6us for stagger), epilogue trimmed from
// 4 -> 3 transcendentals/element (ex2 = exp2(-|s|L2E) reused for sigmoid
// and softplus; p = s<0 ? 1-r : r).
// Model (R6 calibration): fixed harness overhead = 91.6us (poisons+restores+
// gaps); kernels ~17.5us (prep ~5, pair ~12 vs ~9-12 trans-pipe floor:
// 134M v_rcp @ 8cy/wave64 on 1024 SIMDs = 6.8us). Headroom ~3us -> done.
// History: R1 112.3 / R2 112.6 / R3 114.6 / R4 108.9 / R5 FAIL / R6 180.1
// (coop replay overhead; gave the 88.5us dispatch calibration) / R7 109.5.

#define L2E 1.4426950408889634f
#define C2  2.8853900817779268f   // 2*log2(e)
#define LN2 0.6931471805599453f
#define RCP(x) __builtin_amdgcn_rcpf(x)
#define EXP2(x) __builtin_amdgcn_exp2f(x)
#define LOG2(x) __builtin_amdgcn_logf(x)

// ---------------- threefry2x32, key = (0,1) (jax.random.key(1)) -------------
__device__ __forceinline__ void threefry2x32_01(unsigned x0, unsigned x1,
                                                unsigned& o0, unsigned& o1) {
  const unsigned k0 = 0u, k1 = 1u;
  const unsigned k2 = 0x1BD11BDAu ^ k0 ^ k1;  // 0x1BD11BDB
#define TF_R(r) { x0 += x1; x1 = (x1 << r) | (x1 >> (32 - r)); x1 ^= x0; }
  x0 += k0; x1 += k1;
  TF_R(13) TF_R(15) TF_R(26) TF_R(6)
  x0 += k1; x1 += k2 + 1u;
  TF_R(17) TF_R(29) TF_R(16) TF_R(24)
  x0 += k2; x1 += k0 + 2u;
  TF_R(13) TF_R(15) TF_R(26) TF_R(6)
  x0 += k0; x1 += k1 + 3u;
  TF_R(17) TF_R(29) TF_R(16) TF_R(24)
  x0 += k1; x1 += k2 + 4u;
  TF_R(13) TF_R(15) TF_R(26) TF_R(6)
  x0 += k2; x1 += k0 + 5u;
#undef TF_R
  o0 = x0; o1 = x1;
}

__device__ __forceinline__ float tf_uniform(unsigned y) {
  // jax uniform f32: bitcast((bits>>9)|0x3f800000) - 1.0
  return __uint_as_float((y >> 9) | 0x3f800000u) - 1.0f;
}

// ---------------- proj tile (32r x 32c) -------------------------------------
__device__ __forceinline__ void proj_tile(
    float* lds, int t, int tileid, const float* __restrict__ enc,
    const float* __restrict__ wl, const float* __restrict__ wr,
    float* __restrict__ ws) {
  float* As = lds;          // [32][33]
  float* Ws = lds + 1056;   // [32][34]
  const int r0 = (tileid & 63) * 32;
  const int c0 = (tileid >> 6) * 32;
  const float* __restrict__ wmat = (c0 < 64) ? wl : wr;
  const int cbase = c0 & 63;
  const int ty = t >> 4, tx = t & 15;
  float acc[2][2] = {};
  for (int ec = 0; ec < 8; ++ec) {
    {
      const int rr = t >> 3, e4 = (t & 7) * 4;
      const float4 v = *(const float4*)(enc + (r0 + rr) * 256 + ec * 32 + e4);
      As[rr * 33 + e4] = v.x; As[rr * 33 + e4 + 1] = v.y;
      As[rr * 33 + e4 + 2] = v.z; As[rr * 33 + e4 + 3] = v.w;
      const float4 w = *(const float4*)(wmat + (ec * 32 + rr) * 64 + cbase + e4);
      Ws[rr * 34 + e4] = w.x; Ws[rr * 34 + e4 + 1] = w.y;
      Ws[rr * 34 + e4 + 2] = w.z; Ws[rr * 34 + e4 + 3] = w.w;
    }
    __syncthreads();
#pragma unroll
    for (int e = 0; e < 32; ++e) {
      const float a0 = As[(2 * ty) * 33 + e];
      const float a1 = As[(2 * ty + 1) * 33 + e];
      const float2 wv = *(const float2*)&Ws[e * 34 + 2 * tx];
      acc[0][0] = fmaf(a0, wv.x, acc[0][0]);
      acc[0][1] = fmaf(a0, wv.y, acc[0][1]);
      acc[1][0] = fmaf(a1, wv.x, acc[1][0]);
      acc[1][1] = fmaf(a1, wv.y, acc[1][1]);
    }
    __syncthreads();
  }
  const int matoff = (c0 < 64) ? 0 : 131072;
#pragma unroll
  for (int i = 0; i < 2; ++i) {
    const int r = r0 + 2 * ty + i;
    const int b = r >> 10, n = r & 1023;
#pragma unroll
    for (int j = 0; j < 2; ++j) {
      const int c = cbase + 2 * tx + j;
      ws[matoff + b * 65536 + c * 1024 + n] = EXP2(C2 * acc[i][j]);
    }
  }
}

// ---------------- edge MLP (4 rows/block, wave per row) ---------------------
__device__ __forceinline__ void mlp_rows(
    float* lds, int t, int e0, const float* __restrict__ eq,
    const float* __restrict__ w1, const float* __restrict__ b1,
    const float* __restrict__ w2, const float* __restrict__ b2,
    float* __restrict__ wout) {
  float* eql = lds;  // [4][64]
  const int row = t >> 6, lane = t & 63;
  const int e = e0 + row;
  eql[row * 64 + lane] = eq[e * 64 + lane];
  __syncthreads();
  float acc0 = b1[lane], acc1 = b1[lane + 64];
#pragma unroll 8
  for (int k = 0; k < 64; ++k) {
    const float ev = eql[row * 64 + k];
    acc0 = fmaf(ev, w1[k * 128 + lane], acc0);
    acc1 = fmaf(ev, w1[k * 128 + 64 + lane], acc1);
  }
  float v = fmaxf(acc0, 0.0f) * w2[lane] + fmaxf(acc1, 0.0f) * w2[lane + 64];
#pragma unroll
  for (int off = 32; off > 0; off >>= 1) v += __shfl_xor(v, off);
  if (lane == 0) {
    const float l = v + b2[0];
    const float sp = fmaxf(l, 0.0f) + log1pf(expf(-fabsf(l)));
    wout[e] = sp + 1e-8f;
  }
}

__global__ __launch_bounds__(256) void prep_kernel(
    const float* __restrict__ enc, const float* __restrict__ wl,
    const float* __restrict__ wr, float* __restrict__ ws,
    const float* __restrict__ eq, const float* __restrict__ w1,
    const float* __restrict__ b1, const float* __restrict__ w2,
    const float* __restrict__ b2, float* __restrict__ wout) {
  __shared__ float lds[2144];
  const int t = threadIdx.x;
  const int bx = blockIdx.x;
  if (bx < 256) {
    proj_tile(lds, t, bx, enc, wl, wr, ws);
  } else {
    mlp_rows(lds, t, (bx - 256) * 4, eq, w1, b1, w2, b2, wout);
  }
}

// ---------------- pair kernel (R4-proven v3 loop, slim epilogue) ------------
// Tile 32i x 64j, grid (32,16,2) = 1024 blocks (4/CU, 16 waves/CU), 24.8KB.
__global__ __launch_bounds__(256, 4) void pair_kernel(
    const float* __restrict__ ws, const float* __restrict__ u,
    const float* __restrict__ lb, float* __restrict__ out) {
  __shared__ float sA[64 * 32];  // [h][i_local]
  __shared__ float sB[64 * 64];  // [h][j_local]
  __shared__ float sU[64];
  const int t = threadIdx.x;
  const int b = blockIdx.z;
  const int i0 = blockIdx.x * 32;
  const int j0 = blockIdx.y * 64;
  const float* __restrict__ srcA = ws + b * 65536;
  const float* __restrict__ srcB = ws + 131072 + b * 65536;

  {
    const int h = t >> 3, c = (t & 7) * 4;
    *(float4*)(sA + h * 32 + c) = *(const float4*)(srcA + h * 1024 + i0 + c);
    *(float4*)(sA + (h + 32) * 32 + c) =
        *(const float4*)(srcA + (h + 32) * 1024 + i0 + c);
  }
  {
    const int h = t >> 4, c = (t & 15) * 4;
#pragma unroll
    for (int q = 0; q < 4; ++q)
      *(float4*)(sB + (h + 16 * q) * 64 + c) =
          *(const float4*)(srcB + (h + 16 * q) * 1024 + j0 + c);
  }
  if (t < 64) sU[t] = u[t];
  __syncthreads();

  const int ia = (t >> 4) * 2;   // 2 consecutive i (broadcast b64 read)
  const int ja = (t & 15) * 4;   // 4 consecutive j (2-way-free b128 read)
  float acc[2][4] = {};          // acc = sum_h u_h * rcp(A*B + 1)
#pragma unroll
  for (int h4 = 0; h4 < 16; ++h4) {
    const float4 uc = *(const float4*)(sU + h4 * 4);  // 4 u's per b128
#pragma unroll
    for (int hh = 0; hh < 4; ++hh) {
      const int h = h4 * 4 + hh;
      const float uh = (&uc.x)[hh];
      const float2 av = *(const float2*)(sA + h * 32 + ia);
      const float4 bv = *(const float4*)(sB + h * 64 + ja);
      const float a[2] = {av.x, av.y};
      const float bb[4] = {bv.x, bv.y, bv.z, bv.w};
#pragma unroll
      for (int ii = 0; ii < 2; ++ii)
#pragma unroll
        for (int jj = 0; jj < 4; ++jj)
          acc[ii][jj] = fmaf(uh, RCP(fmaf(a[ii], bb[jj], 1.0f)), acc[ii][jj]);
    }
  }

  // s = sum(u) + l_bias - 2*acc ; butterfly-reduce sum(u)
  float uv = sU[t & 63];
#pragma unroll
  for (int off = 32; off > 0; off >>= 1) uv += __shfl_xor(uv, off);
  const float su = uv + lb[0];

  float* __restrict__ outS = out + b * 1048576;
  float* __restrict__ outM = out + 2097152 + b * 1048576;
  float* __restrict__ outE = out + 4194304 + b * 1048576;
#pragma unroll
  for (int ii = 0; ii < 2; ++ii) {
    const int gi = i0 + ia + ii;
    const unsigned mb = (unsigned)(gi * 1024 + j0 + ja);
    float4 sv, ev, smv;
#pragma unroll
    for (int jj = 0; jj < 4; ++jj) {
      const int gj = j0 + ja + jj;
      // jax counter pair (m, m+2^20): out0 -> b=0 sample, out1 -> b=1 sample
      unsigned y0, y1;
      threefry2x32_01(mb + (unsigned)jj, mb + (unsigned)jj + 1048576u, y0, y1);
      const float uu = tf_uniform(b ? y1 : y0);
      float s = fmaf(-2.0f, acc[ii][jj], su);
      if (gi == gj) s -= 1e8f;               // diagonal mask
      // 3-transcendental epilogue: ex2 = 2^(-|s|*log2e) = e^{-|s|}
      const float ex2 = EXP2(-fabsf(s) * L2E);
      const float r = RCP(1.0f + ex2);       // = sigmoid(|s|)
      const float p = (s < 0.0f) ? (1.0f - r) : r;   // sigmoid(s)
      const float ent = fmaxf(s, 0.0f) + LOG2(1.0f + ex2) * LN2 - s * p;
      (&sv.x)[jj] = s;
      (&ev.x)[jj] = ent;
      (&smv.x)[jj] = (uu < p) ? 1.0f : 0.0f;
    }
    const int base = gi * 1024 + j0 + ja;
    *(float4*)(outS + base) = smv;
    *(float4*)(outM + base) = sv;
    *(float4*)(outE + base) = ev;
  }
}

extern "C" void kernel_launch(void* const* d_in, const int* in_sizes, int n_in,
                              void* d_out, int out_size, void* d_ws, size_t ws_size,
                              hipStream_t stream) {
  const float* enc = (const float*)d_in[0];   // [2,1024,256]
  const float* wl  = (const float*)d_in[1];   // [256,64]
  const float* wr  = (const float*)d_in[2];   // [256,64]
  const float* u   = (const float*)d_in[3];   // [64]
  const float* lb  = (const float*)d_in[4];   // [1]
  const float* eq  = (const float*)d_in[5];   // [1024,64]
  const float* w1  = (const float*)d_in[6];   // [64,128]
  const float* b1  = (const float*)d_in[7];   // [128]
  const float* w2  = (const float*)d_in[8];   // [128,1]
  const float* b2  = (const float*)d_in[9];   // [1]
  float* out = (float*)d_out;
  float* wsf = (float*)d_ws;                  // 262144 floats = 1MB used

  prep_kernel<<<320, 256, 0, stream>>>(enc, wl, wr, wsf, eq, w1, b1, w2, b2,
                                       out + 6291456);
  pair_kernel<<<dim3(32, 16, 2), 256, 0, stream>>>(wsf, u, lb, out);
}